// Round 1
// 2611.624 us; speedup vs baseline: 1.2732x; 1.2732x over previous
//
#include <hip/hip_runtime.h>
#include <cstdint>
#include <cstddef>

// Problem constants: V=50000, E=300, NF=1, H=256, B=128, TH=32, TB=512, NC=4.
#define H_    256
#define NG    768      // 512 gate cols (r|u) + 256 candidate cols, packed
#define BATCH 128
#define TH_   32
#define TB_   512
#define E_    300
#define RPB   16             // batch rows per gru block
#define NBLK  (BATCH / RPB)  // 8 row-groups per gru job

typedef _Float16 half8 __attribute__((ext_vector_type(8)));
typedef _Float16 half4 __attribute__((ext_vector_type(4)));
typedef float    floatx4 __attribute__((ext_vector_type(4)));

#define AS1 __attribute__((address_space(1)))
#define AS3 __attribute__((address_space(3)))

// s_waitcnt immediates (gfx9 encoding: vmcnt[3:0]=imm[3:0], vmcnt[5:4]=imm[15:14],
// expcnt=imm[6:4], lgkmcnt=imm[11:8]).
#define WC_LGKM0 0xC07F   // lgkmcnt(0), vmcnt/exp unconstrained
#define WC_VM14  0x0F7E   // vmcnt(14) only
#define WC_VM6   0x0F76   // vmcnt(6)  only
#define WC_VM0   0x0F70   // vmcnt(0)  only

// ---------------------------------------------------------------------------
// bias[j] = [bg | bc] (768)
// ---------------------------------------------------------------------------
__global__ __launch_bounds__(256) void pack_bias(
    const float* __restrict__ bg, const float* __restrict__ bc,
    float* __restrict__ bias)
{
  int idx = blockIdx.x * 256 + threadIdx.x;
  if (idx < NG) bias[idx] = (idx < 2 * H_) ? bg[idx] : bc[idx - 2 * H_];
}

// ---------------------------------------------------------------------------
// Pack INPUT-projection weights into fp16 MFMA B-frag tiles.
// ---------------------------------------------------------------------------
__global__ __launch_bounds__(256) void pack_bx(
    const float* __restrict__ Wg, const float* __restrict__ Wc,
    int din, int KT, _Float16* __restrict__ out)
{
  int idx = blockIdx.x * 256 + threadIdx.x;
  if (idx >= KT * 48 * 64) return;
  int lane = idx & 63, tile = idx >> 6;
  int kt = tile / 48, nt = tile - kt * 48;
  int col = nt * 16 + (lane & 15);
  int k0 = kt * 32 + (lane >> 4) * 8;
  const float* W; int ncols, c2;
  if (col < 2 * H_) { W = Wg; ncols = 2 * H_; c2 = col; }
  else              { W = Wc; ncols = H_;     c2 = col - 2 * H_; }
  _Float16* dst = out + ((size_t)(kt * 48 + nt) * 64 + lane) * 8;
#pragma unroll
  for (int j = 0; j < 8; ++j) {
    int k = k0 + j;
    dst[j] = (k < din) ? (_Float16)W[(size_t)k * ncols + c2] : (_Float16)0.f;
  }
}

// ---------------------------------------------------------------------------
// Pack recurrent weights into fp16 MFMA B-fragment order (R7-validated).
// ---------------------------------------------------------------------------
__global__ __launch_bounds__(256) void pack_w(
    const float* __restrict__ Wg, const float* __restrict__ Wc, int din,
    _Float16* __restrict__ wpk)
{
  int idx = blockIdx.x * 256 + threadIdx.x;
  if (idx >= 48 * 64) return;
  int tile = idx >> 6, lane = idx & 63;
  int grp = tile >> 4, tt = tile & 15;
  int wv = tt >> 1, s = tt & 1;
  const float* W; int ncols, n0;
  if (grp == 0)      { W = Wg; ncols = 2 * H_; n0 = wv * 32 + s * 16; }
  else if (grp == 1) { W = Wg; ncols = 2 * H_; n0 = 256 + wv * 32 + s * 16; }
  else               { W = Wc; ncols = H_;     n0 = wv * 32 + s * 16; }
  int n = n0 + (lane & 15);
  int kb = (lane >> 4) * 8;
#pragma unroll
  for (int kt = 0; kt < 8; ++kt) {
    _Float16* dst = wpk + ((size_t)(tile * 8 + kt) * 64 + lane) * 8;
#pragma unroll
    for (int j = 0; j < 8; ++j)
      dst[j] = (_Float16)W[(size_t)(din + kt * 32 + kb + j) * ncols + n];
  }
}

// ---------------------------------------------------------------------------
// seqlen[b] = #nonzero ids in row b (valid steps form a prefix).
// ---------------------------------------------------------------------------
__global__ __launch_bounds__(256) void seq_k(const int* __restrict__ ids, int T,
                                             int* __restrict__ seq)
{
  __shared__ int red[256];
  int b = blockIdx.x, tid = threadIdx.x;
  int cnt = 0;
  for (int t = tid; t < T; t += 256) cnt += (ids[b * T + t] != 0) ? 1 : 0;
  red[tid] = cnt;
  __syncthreads();
  for (int s = 128; s > 0; s >>= 1) {
    if (tid < s) red[tid] += red[tid + s];
    __syncthreads();
  }
  if (tid == 0) seq[b] = red[0];
}

// ---------------------------------------------------------------------------
// Stage job descriptors: one mega dispatch runs up to 4 gru jobs (blocks
// first, 8 blocks each -> scheduled onto CUs first) and up to 4 gemm jobs
// on the remaining CUs. All producer->consumer edges are across dispatches.
// ---------------------------------------------------------------------------
struct GruJob {
  const float* G; const _Float16* W; const int* seq;
  float* outp; float* state; int t0; int tc;
};
struct GemmJob {
  const float* Adir; const int* ids; const _Float16* Bpk;
  const float* bias; float* G;
  int K; int KT; int t0; int tcsh; int T;
};
struct StageArgs {
  GruJob  gj[4];
  GemmJob mj[4];
  const float* emb;
  int ngru; int ngemm;
  int goff[4];          // gemm-local block offsets (prefix sums)
};

union SMem {
  struct { _Float16 hpk[4096]; _Float16 rpk[4096]; float Gs[2][12288]; } g;
  struct { _Float16 Al[2][64 * 40]; _Float16 Bl[2][8 * 512]; } m;
};

// ---------------------------------------------------------------------------
// MFMA input-projection GEMM block (R10 kernel re-laned for 512 threads:
// 8 waves, each owns one 16-col strip; tile M=64 x N=128, K in 32-ktiles).
// Output: fragment-packed G (R9-validated layout, consumed by gru blocks).
// ---------------------------------------------------------------------------
__device__ __forceinline__ void gemm_block(const GemmJob& jb, const float* emb,
                                           int lb, SMem& sm)
{
  auto& Al = sm.m.Al;
  auto& Bl = sm.m.Bl;
  const int tid = threadIdx.x;
  const int w = tid >> 6, lane = tid & 63;
  const int quad = lane >> 4, l15 = lane & 15;
  const int gx = lb / 6, gy = lb - gx * 6;
  const int m0 = gx * 64, n0 = gy * 128;
  const int K = jb.K, KT = jb.KT, tcsh = jb.tcsh;
  const int tc = 1 << tcsh;

  // A-load mapping: row am = tid>>3 (0..63), k-octant ak = tid&7 (4 floats)
  const int am = tid >> 3, ak = tid & 7;
  const int arow = m0 + am;
  const float* asrc;
  if (jb.Adir) {
    asrc = jb.Adir + (size_t)arow * K;
  } else {
    int b = arow >> tcsh, tl = arow & (tc - 1);
    asrc = emb + (size_t)jb.ids[b * jb.T + jb.t0 + tl] * K;
  }

  float a4[4];
  auto loadA = [&](int kt) {
    int k0 = kt * 32 + ak * 4;
#pragma unroll
    for (int j = 0; j < 4; ++j) a4[j] = (k0 + j < K) ? asrc[k0 + j] : 0.f;
  };
  auto writeA = [&](int buf) {
    half4 v;
#pragma unroll
    for (int j = 0; j < 4; ++j) v[j] = (_Float16)a4[j];
    *(half4*)&Al[buf][am * 40 + ak * 4] = v;
  };
  auto stageB = [&](int kt, int buf) {
    int nt = (n0 >> 4) + w;
    const _Float16* src = jb.Bpk + ((size_t)(kt * 48 + nt) * 64 + lane) * 8;
    __builtin_amdgcn_global_load_lds(
        (const AS1 unsigned int*)src,
        (AS3 unsigned int*)&Bl[buf][w * 512 + lane * 8], 16, 0, 0);
  };

  loadA(0);
  stageB(0, 0);
  writeA(0);
  floatx4 acc[4] = {};

  for (int kt = 0; kt < KT; ++kt) {
    const int buf = kt & 1;
    __syncthreads();                       // buf fully staged for all waves
    if (kt + 1 < KT) { loadA(kt + 1); stageB(kt + 1, buf ^ 1); }
    half8 bf = *(const half8*)&Bl[buf][w * 512 + lane * 8];
#pragma unroll
    for (int st = 0; st < 4; ++st) {
      half8 af = *(const half8*)&Al[buf][(st * 16 + l15) * 40 + quad * 8];
      acc[st] = __builtin_amdgcn_mfma_f32_16x16x32_f16(af, bf, acc[st], 0, 0, 0);
    }
    if (kt + 1 < KT) writeA(buf ^ 1);      // buf^1 free: all reads done pre-sync
  }

  // epilogue: bias + fragment-packed G stores
  int col = n0 + w * 16 + l15;
  float bb = jb.bias[col];
  int g = col >> 8, kk = col & 255;
  int ww = kk >> 5, ss = (kk >> 4) & 1, ll = kk & 15;
  int cc = 2 * g + ss;
#pragma unroll
  for (int st = 0; st < 4; ++st) {
#pragma unroll
    for (int r = 0; r < 4; ++r) {
      int grow = m0 + st * 16 + quad * 4 + r;
      int b = grow >> tcsh, tl = grow & (tc - 1);
      int rg = b >> 4, mm = b & 15, qb = mm >> 2, rb = mm & 3;
      jb.G[((size_t)tl * BATCH + rg * RPB) * NG +
           ((ww * 6 + cc) * 64 + qb * 16 + ll) * 4 + rb] = acc[st][r] + bb;
    }
  }
}

// ---------------------------------------------------------------------------
// Persistent-weight fused GRU block (R9 inner loop, unchanged numerics).
// ---------------------------------------------------------------------------
__device__ __forceinline__ void gru_block(const GruJob& jb, int rg, SMem& sm)
{
  _Float16* hpk = sm.g.hpk;
  _Float16* rpk = sm.g.rpk;
  auto& Gs = sm.g.Gs;

  const float* G = jb.G;
  if (!G) return;
  const _Float16* Wsrc = jb.W;
  float* outp = jb.outp;
  float* state = jb.state;
  const int t0 = jb.t0, tc = jb.tc;

  const int tid = threadIdx.x;
  const int w = tid >> 6, lane = tid & 63;
  const int quad = lane >> 4, l15 = lane & 15;

  // --- load weights once; pin (blocks rematerialization/sinking) ----------
  floatx4 wg[4][8];   // gate tiles -> VGPRs
  floatx4 wc[2][8];   // candidate tiles -> AGPRs
#pragma unroll
  for (int i = 0; i < 4; ++i) {
    const int tile = (i >> 1) * 16 + w * 2 + (i & 1);
#pragma unroll
    for (int kt = 0; kt < 8; ++kt) {
      wg[i][kt] = *(const floatx4*)&Wsrc[((size_t)(tile * 8 + kt) * 64 + lane) * 8];
      asm volatile("" : "+v"(wg[i][kt]));
    }
  }
#pragma unroll
  for (int i = 0; i < 2; ++i) {
    const int tile = 32 + w * 2 + i;
#pragma unroll
    for (int kt = 0; kt < 8; ++kt) {
      wc[i][kt] = *(const floatx4*)&Wsrc[((size_t)(tile * 8 + kt) * 64 + lane) * 8];
      asm volatile("" : "+a"(wc[i][kt]));
    }
  }

  // --- seq / steps ---------------------------------------------------------
  int seq4[4];
#pragma unroll
  for (int r = 0; r < 4; ++r) seq4[r] = jb.seq[rg * RPB + quad * 4 + r];
  int Smax = 0;
#pragma unroll
  for (int i = 0; i < 16; ++i) Smax = max(Smax, jb.seq[rg * RPB + i]);
  int steps = Smax - t0;
  if (steps < 0) steps = 0;
  if (steps > tc) steps = tc;

  // --- frag addressing (R7-validated bank-exact layout) --------------------
  const int wbase = (w * 64 + quad * 2 + (l15 >> 3)) * 8 + (l15 & 7);
  const int rbase = (((quad >> 1) << 5) + ((l15 & 3) << 3) +
                     ((l15 >> 2) << 1) + (quad & 1)) * 8;

  // --- h_reg init + h frag fill -------------------------------------------
  float h_reg[2][4];
#pragma unroll
  for (int s = 0; s < 2; ++s)
#pragma unroll
    for (int r = 0; r < 4; ++r) {
      int row = quad * 4 + r, k = w * 32 + s * 16 + l15;
      float v = (t0 == 0) ? 0.f : state[(size_t)(rg * RPB + row) * H_ + k];
      h_reg[s][r] = v;
      hpk[wbase + s * 256 + r * 64] = (_Float16)v;
    }

  // --- async G staging: wave w copies its own 6 chunks (1 KB each) --------
  const float* gblk = G + (size_t)rg * RPB * NG + w * (6 * 256);
  float* ldsw = &Gs[0][0] + w * (6 * 256);
  auto stage = [&](int t, int buf) {
    const float* gp = gblk + (size_t)t * BATCH * NG;
    float* lp = ldsw + buf * 12288;
#pragma unroll
    for (int c = 0; c < 6; ++c) {
      __builtin_amdgcn_global_load_lds(
          (const AS1 unsigned int*)(gp + c * 256 + lane * 4),
          (AS3 unsigned int*)(lp + c * 256), 16, 0, 0);
    }
  };
  if (steps > 0) stage(0, 0);
  __syncthreads();   // one full drain: loads for t=0 complete + hpk visible

  const _Float16* hA = &hpk[rbase];
  const _Float16* rA = &rpk[rbase];

  for (int t = 0; t < steps; ++t) {
    const int buf = t & 1;
    const bool staged = (t + 1 < steps);
    if (staged) stage(t + 1, buf ^ 1);   // async prefetch next step's G

    // ---------------- phase A: 4 gate tiles (r s=0,1 ; u s=0,1) ----------
    floatx4 acc[4] = {};
#pragma unroll
    for (int kt = 0; kt < 8; ++kt) {
      half8 a = *(const half8*)&hA[kt * 512];
#pragma unroll
      for (int s = 0; s < 4; ++s)
        acc[s] = __builtin_amdgcn_mfma_f32_16x16x32_f16(
            a, __builtin_bit_cast(half8, wg[s][kt]), acc[s], 0, 0, 0);
    }

    if (staged) {
      if (outp) __builtin_amdgcn_s_waitcnt(WC_VM14);
      else      __builtin_amdgcn_s_waitcnt(WC_VM6);
    } else {
      __builtin_amdgcn_s_waitcnt(WC_VM0);
    }

    floatx4 gA[4];
#pragma unroll
    for (int c = 0; c < 4; ++c)
      gA[c] = *(const floatx4*)&Gs[buf][(w * 6 + c) * 256 + lane * 4];

#pragma unroll
    for (int s = 0; s < 2; ++s)
#pragma unroll
      for (int r = 0; r < 4; ++r) {
        float pre = acc[s][r] + gA[s][r];
        float g = __builtin_amdgcn_rcpf(1.f + __expf(-pre));
        rpk[wbase + s * 256 + r * 64] = (_Float16)(g * h_reg[s][r]);
      }
    float u_reg[2][4];
#pragma unroll
    for (int s = 0; s < 2; ++s)
#pragma unroll
      for (int r = 0; r < 4; ++r) {
        float pre = acc[2 + s][r] + gA[2 + s][r];
        u_reg[s][r] = __builtin_amdgcn_rcpf(1.f + __expf(-pre));
      }
    __builtin_amdgcn_s_waitcnt(WC_LGKM0);   // rpk visible
    __builtin_amdgcn_s_barrier();

    // ---------------- phase B: 2 candidate tiles --------------------------
    floatx4 accB[2] = {};
#pragma unroll
    for (int kt = 0; kt < 8; ++kt) {
      half8 a = *(const half8*)&rA[kt * 512];
#pragma unroll
      for (int s = 0; s < 2; ++s)
        accB[s] = __builtin_amdgcn_mfma_f32_16x16x32_f16(
            a, __builtin_bit_cast(half8, wc[s][kt]), accB[s], 0, 0, 0);
    }
    floatx4 gB[2];
#pragma unroll
    for (int s = 0; s < 2; ++s)
      gB[s] = *(const floatx4*)&Gs[buf][(w * 6 + 4 + s) * 256 + lane * 4];

#pragma unroll
    for (int s = 0; s < 2; ++s)
#pragma unroll
      for (int r = 0; r < 4; ++r) {
        int row = quad * 4 + r;
        float pre = accB[s][r] + gB[s][r];
        float c = 1.f - 2.f * __builtin_amdgcn_rcpf(1.f + __expf(2.f * pre));
        float u = u_reg[s][r];
        float hn = u * h_reg[s][r] + (1.f - u) * c;
        bool valid = (t0 + t) < seq4[r];
        hn = valid ? hn : h_reg[s][r];
        h_reg[s][r] = hn;
        hpk[wbase + s * 256 + r * 64] = (_Float16)hn;
        if (outp)
          outp[((size_t)(rg * RPB + row) * tc + t) * H_ + (w * 32 + s * 16 + l15)] =
              valid ? hn : 0.f;
      }
    __builtin_amdgcn_s_waitcnt(WC_LGKM0);   // hpk visible
    __builtin_amdgcn_s_barrier();
  }
  // --- save state from fp32 masters ---------------------------------------
#pragma unroll
  for (int s = 0; s < 2; ++s)
#pragma unroll
    for (int r = 0; r < 4; ++r)
      state[(size_t)(rg * RPB + quad * 4 + r) * H_ + (w * 32 + s * 16 + l15)] =
          h_reg[s][r];
}

// ---------------------------------------------------------------------------
// Mega dispatch: gru blocks first (get CUs first), gemm blocks fill the rest.
// ---------------------------------------------------------------------------
__global__ __launch_bounds__(512, 1) void mega(StageArgs a)
{
  __shared__ SMem sm;
  const int bid = blockIdx.x;
  const int ngrub = a.ngru * NBLK;
  if (bid < ngrub) {
    gru_block(a.gj[bid >> 3], bid & 7, sm);
  } else {
    int lb = bid - ngrub;
    int j = 0;
#pragma unroll
    for (int k = 1; k < 4; ++k)
      if (k < a.ngemm && lb >= a.goff[k]) j = k;
    gemm_block(a.mj[j], a.emb, lb - a.goff[j], sm);
  }
}

// ---------------------------------------------------------------------------
// Final prediction: out[b, c] = [h_head | h_body] @ W_pred + b_pred.
// ---------------------------------------------------------------------------
__global__ __launch_bounds__(512) void pred_k(
    const float* __restrict__ hh, const float* __restrict__ hb,
    const float* __restrict__ Wp, const float* __restrict__ bpred,
    float* __restrict__ out)
{
  int tid = threadIdx.x;
  int b = tid >> 2, c = tid & 3;
  float acc = bpred[c];
  for (int k = 0; k < H_; ++k) acc += hh[b * H_ + k] * Wp[k * 4 + c];
  for (int k = 0; k < H_; ++k) acc += hb[b * H_ + k] * Wp[(H_ + k) * 4 + c];
  out[b * 4 + c] = acc;
}

// ---------------------------------------------------------------------------
extern "C" void kernel_launch(void* const* d_in, const int* in_sizes, int n_in,
                              void* d_out, int out_size, void* d_ws, size_t ws_size,
                              hipStream_t stream)
{
  (void)in_sizes; (void)n_in; (void)out_size;
  const int*   idsH = (const int*)  d_in[0];
  const int*   idsB = (const int*)  d_in[1];
  const float* emb  = (const float*)d_in[2];
  const float* Wp   = (const float*)d_in[3];
  const float* bp   = (const float*)d_in[4];
  const float* W[4][4];   // [hd0,hd1,bd0,bd1][Wg,bg,Wc,bc]
  for (int s = 0; s < 4; ++s)
    for (int q = 0; q < 4; ++q)
      W[s][q] = (const float*)d_in[5 + s * 4 + q];

  float* wbase = (float*)d_ws;
  size_t off = 0;
  auto alloc = [&](size_t n) {
    float* p = wbase + off; off += (n + 255) & ~(size_t)255; return p;
  };
  int* seqH = (int*)alloc(BATCH);
  int* seqB = (int*)alloc(BATCH);
  float* bi[4]; _Float16* Wpk[4]; _Float16* Bxh[4];
  const int din[4] = {E_, H_, E_, H_};
  const int KT[4]  = {10, 8, 10, 8};        // ceil(din/32)
  for (int s = 0; s < 4; ++s) {
    bi[s]  = alloc(NG);
    Wpk[s] = (_Float16*)alloc(48 * 8 * 64 * 8 / 2);
    Bxh[s] = (_Float16*)alloc((size_t)KT[s] * 48 * 64 * 8 / 2);
  }
  float* stB0 = alloc((size_t)BATCH * H_);
  float* stH0 = alloc((size_t)BATCH * H_);
  float* hfH  = alloc((size_t)BATCH * H_);
  float* hfB  = alloc((size_t)BATCH * H_);

  // headline buffers (single-buffered; head jobs are spaced 2 stages apart)
  const int CHH = 16;                        // TH/CHH = 2 head chunks
  float* GH0 = alloc((size_t)BATCH * CHH * NG);
  float* GH1 = alloc((size_t)BATCH * CHH * NG);
  float* OcH = alloc((size_t)BATCH * CHH * H_);

  // body chunk size: 16 steps (falls back if ws is tight)
  int CH = 16;
  while (CH > 4 &&
         (off + 2 * (size_t)BATCH * CH * (2 * NG + H_) + 2048) * 4 > ws_size)
    CH >>= 1;
  float *GB0[2], *GB1[2], *OcB[2];
  for (int i = 0; i < 2; ++i) {
    GB0[i] = alloc((size_t)BATCH * CH * NG);
    GB1[i] = alloc((size_t)BATCH * CH * NG);
    OcB[i] = alloc((size_t)BATCH * CH * H_);
  }
  const int tcshB = __builtin_ctz(CH), tcshH = __builtin_ctz(CHH);
  const int NB = TB_ / CH;

  // 1. pack weights + seqlens
  for (int s = 0; s < 4; ++s) {
    pack_bias<<<(NG + 255) / 256, 256, 0, stream>>>(W[s][1], W[s][3], bi[s]);
    pack_w<<<(48 * 64 + 255) / 256, 256, 0, stream>>>(
        W[s][0], W[s][2], din[s], Wpk[s]);
    pack_bx<<<(KT[s] * 48 * 64 + 255) / 256, 256, 0, stream>>>(
        W[s][0], W[s][2], din[s], KT[s], Bxh[s]);
  }
  seq_k<<<BATCH, 256, 0, stream>>>(idsH, TH_, seqH);
  seq_k<<<BATCH, 256, 0, stream>>>(idsB, TB_, seqB);

  // 2. lag-2 software pipeline of mega dispatches.
  //    Stage s: gemm0(s) | gruL0(s-1) | gemm1(s-2) | gruL1(s-3)   (body)
  //    Headline rides along in stages 0..5 at half rate (single buffers).
  const int nstages = (NB + 3 > 6) ? NB + 3 : 6;
  for (int s = 0; s < nstages; ++s) {
    StageArgs a{};
    a.emb = emb;
    int ng = 0, nm = 0, gacc = 0;
    auto addGru = [&](const float* G, const _Float16* Wk, const int* seq,
                      float* outp, float* st, int t0, int tc) {
      a.gj[ng++] = GruJob{G, Wk, seq, outp, st, t0, tc};
    };
    auto addGemm = [&](const float* Adir, const int* ids, const _Float16* Bpk,
                       const float* bias, float* G, int K, int KTv, int t0,
                       int tcsh, int T, int rows) {
      a.goff[nm] = gacc; gacc += (rows / 64) * 6;
      a.mj[nm++] = GemmJob{Adir, ids, Bpk, bias, G, K, KTv, t0, tcsh, T};
    };

    // ---- body ----
    if (s < NB)
      addGemm(nullptr, idsB, Bxh[2], bi[2], GB0[s & 1], E_, 10, s * CH,
              tcshB, TB_, BATCH * CH);
    if (s >= 1 && s <= NB) {
      int c = s - 1;
      addGru(GB0[c & 1], Wpk[2], seqB, OcB[c & 1], stB0, c * CH, CH);
    }
    if (s >= 2 && s <= NB + 1) {
      int c = s - 2;
      addGemm(OcB[c & 1], nullptr, Bxh[3], bi[3], GB1[c & 1], H_, 8, 0,
              tcshB, TB_, BATCH * CH);
    }
    if (s >= 3 && s <= NB + 2) {
      int c = s - 3;
      addGru(GB1[c & 1], Wpk[3], seqB, nullptr, hfB, c * CH, CH);
    }
    // ---- headline ----
    if (s == 0 || s == 2)
      addGemm(nullptr, idsH, Bxh[0], bi[0], GH0, E_, 10, (s >> 1) * CHH,
              tcshH, TH_, BATCH * CHH);
    if (s == 1 || s == 3)
      addGru(GH0, Wpk[0], seqH, OcH, stH0, ((s - 1) >> 1) * CHH, CHH);
    if (s == 2 || s == 4)
      addGemm(OcH, nullptr, Bxh[1], bi[1], GH1, H_, 8, 0, tcshH, TH_,
              BATCH * CHH);
    if (s == 3 || s == 5)
      addGru(GH1, Wpk[1], seqH, nullptr, hfH, ((s - 3) >> 1) * CHH, CHH);

    a.ngru = ng; a.ngemm = nm;
    int nblocks = ng * NBLK + gacc;
    if (nblocks > 0) mega<<<nblocks, 512, 0, stream>>>(a);
  }

  // 3. prediction head
  pred_k<<<1, 512, 0, stream>>>(hfH, hfB, Wp, bp, (float*)d_out);
}

// Round 2
// 2532.877 us; speedup vs baseline: 1.3128x; 1.0311x over previous
//
#include <hip/hip_runtime.h>
#include <cstdint>
#include <cstddef>

// Problem constants: V=50000, E=300, NF=1, H=256, B=128, TH=32, TB=512, NC=4.
#define H_    256
#define NG    768      // 512 gate cols (r|u) + 256 candidate cols, packed
#define BATCH 128
#define TH_   32
#define TB_   512
#define E_    300
#define RPB   16             // batch rows per gru block
#define NBLK  (BATCH / RPB)  // 8 row-groups per gru job

typedef _Float16 half8 __attribute__((ext_vector_type(8)));
typedef _Float16 half4 __attribute__((ext_vector_type(4)));
typedef float    floatx4 __attribute__((ext_vector_type(4)));

#define AS1 __attribute__((address_space(1)))
#define AS3 __attribute__((address_space(3)))

// s_waitcnt immediates (gfx9 encoding: vmcnt[3:0]=imm[3:0], vmcnt[5:4]=imm[15:14],
// expcnt=imm[6:4], lgkmcnt=imm[11:8]).
#define WC_LGKM0 0xC07F   // lgkmcnt(0), vmcnt/exp unconstrained
#define WCVM(N)  (0x0F70 | ((N) & 15) | (((N) >> 4) << 14))   // vmcnt(N) only

// ---------------------------------------------------------------------------
// bias[j] = [bg | bc] (768)
// ---------------------------------------------------------------------------
__global__ __launch_bounds__(256) void pack_bias(
    const float* __restrict__ bg, const float* __restrict__ bc,
    float* __restrict__ bias)
{
  int idx = blockIdx.x * 256 + threadIdx.x;
  if (idx < NG) bias[idx] = (idx < 2 * H_) ? bg[idx] : bc[idx - 2 * H_];
}

// ---------------------------------------------------------------------------
// Pack INPUT-projection weights into fp16 MFMA B-frag tiles.
// ---------------------------------------------------------------------------
__global__ __launch_bounds__(256) void pack_bx(
    const float* __restrict__ Wg, const float* __restrict__ Wc,
    int din, int KT, _Float16* __restrict__ out)
{
  int idx = blockIdx.x * 256 + threadIdx.x;
  if (idx >= KT * 48 * 64) return;
  int lane = idx & 63, tile = idx >> 6;
  int kt = tile / 48, nt = tile - kt * 48;
  int col = nt * 16 + (lane & 15);
  int k0 = kt * 32 + (lane >> 4) * 8;
  const float* W; int ncols, c2;
  if (col < 2 * H_) { W = Wg; ncols = 2 * H_; c2 = col; }
  else              { W = Wc; ncols = H_;     c2 = col - 2 * H_; }
  _Float16* dst = out + ((size_t)(kt * 48 + nt) * 64 + lane) * 8;
#pragma unroll
  for (int j = 0; j < 8; ++j) {
    int k = k0 + j;
    dst[j] = (k < din) ? (_Float16)W[(size_t)k * ncols + c2] : (_Float16)0.f;
  }
}

// ---------------------------------------------------------------------------
// Pack recurrent weights into fp16 MFMA B-fragment order (R7-validated).
// ---------------------------------------------------------------------------
__global__ __launch_bounds__(256) void pack_w(
    const float* __restrict__ Wg, const float* __restrict__ Wc, int din,
    _Float16* __restrict__ wpk)
{
  int idx = blockIdx.x * 256 + threadIdx.x;
  if (idx >= 48 * 64) return;
  int tile = idx >> 6, lane = idx & 63;
  int grp = tile >> 4, tt = tile & 15;
  int wv = tt >> 1, s = tt & 1;
  const float* W; int ncols, n0;
  if (grp == 0)      { W = Wg; ncols = 2 * H_; n0 = wv * 32 + s * 16; }
  else if (grp == 1) { W = Wg; ncols = 2 * H_; n0 = 256 + wv * 32 + s * 16; }
  else               { W = Wc; ncols = H_;     n0 = wv * 32 + s * 16; }
  int n = n0 + (lane & 15);
  int kb = (lane >> 4) * 8;
#pragma unroll
  for (int kt = 0; kt < 8; ++kt) {
    _Float16* dst = wpk + ((size_t)(tile * 8 + kt) * 64 + lane) * 8;
#pragma unroll
    for (int j = 0; j < 8; ++j)
      dst[j] = (_Float16)W[(size_t)(din + kt * 32 + kb + j) * ncols + n];
  }
}

// ---------------------------------------------------------------------------
// seqlen[b] = #nonzero ids in row b (valid steps form a prefix).
// ---------------------------------------------------------------------------
__global__ __launch_bounds__(256) void seq_k(const int* __restrict__ ids, int T,
                                             int* __restrict__ seq)
{
  __shared__ int red[256];
  int b = blockIdx.x, tid = threadIdx.x;
  int cnt = 0;
  for (int t = tid; t < T; t += 256) cnt += (ids[b * T + t] != 0) ? 1 : 0;
  red[tid] = cnt;
  __syncthreads();
  for (int s = 128; s > 0; s >>= 1) {
    if (tid < s) red[tid] += red[tid + s];
    __syncthreads();
  }
  if (tid == 0) seq[b] = red[0];
}

// ---------------------------------------------------------------------------
// Stage job descriptors.
// ---------------------------------------------------------------------------
struct GruJob {
  const _Float16* G; const _Float16* W; const int* seq;
  _Float16* outp; float* state; int t0; int tc;
};
struct GemmJob {
  const _Float16* Adir; const int* ids; const _Float16* Bpk;
  const float* bias; _Float16* G;
  int K; int KT; int t0; int tcsh; int T;
};
struct StageArgs {
  GruJob  gj[4];
  GemmJob mj[4];
  const float* emb;
  int ngru; int ngemm;
  int goff[4];          // gemm-local block offsets (prefix sums)
};

union SMem {
  struct { _Float16 hpk[4096]; _Float16 rpk[4096]; _Float16 Gs[4][12288]; } g;
  struct { _Float16 Al[2][64 * 40]; _Float16 Bl[2][8 * 512]; } m;
};

// ---------------------------------------------------------------------------
// MFMA input-projection GEMM block (512 threads: 8 waves, one 16-col strip
// each; tile M=64 x N=128, K in 32-ktiles). Output: fragment-packed fp16 G.
// ---------------------------------------------------------------------------
__device__ __forceinline__ void gemm_block(const GemmJob& jb, const float* emb,
                                           int lb, SMem& sm)
{
  auto& Al = sm.m.Al;
  auto& Bl = sm.m.Bl;
  const int tid = threadIdx.x;
  const int w = tid >> 6, lane = tid & 63;
  const int quad = lane >> 4, l15 = lane & 15;
  const int gx = lb / 6, gy = lb - gx * 6;
  const int m0 = gx * 64, n0 = gy * 128;
  const int K = jb.K, KT = jb.KT, tcsh = jb.tcsh;
  const int tc = 1 << tcsh;

  // A-load mapping: row am = tid>>3 (0..63), k-octant ak = tid&7 (4 elems)
  const int am = tid >> 3, ak = tid & 7;
  const int arow = m0 + am;
  const _Float16* asrch = nullptr;
  const float*    asrcf = nullptr;
  if (jb.Adir) {
    asrch = jb.Adir + (size_t)arow * K;
  } else {
    int b = arow >> tcsh, tl = arow & (tc - 1);
    asrcf = emb + (size_t)jb.ids[b * jb.T + jb.t0 + tl] * K;
  }

  float a4[4];
  auto loadA = [&](int kt) {
    int k0 = kt * 32 + ak * 4;
    if (asrch) {
      half4 hv = *(const half4*)&asrch[k0];   // K=256: always in-bounds
#pragma unroll
      for (int j = 0; j < 4; ++j) a4[j] = (float)hv[j];
    } else {
#pragma unroll
      for (int j = 0; j < 4; ++j) a4[j] = (k0 + j < K) ? asrcf[k0 + j] : 0.f;
    }
  };
  auto writeA = [&](int buf) {
    half4 v;
#pragma unroll
    for (int j = 0; j < 4; ++j) v[j] = (_Float16)a4[j];
    *(half4*)&Al[buf][am * 40 + ak * 4] = v;
  };
  auto stageB = [&](int kt, int buf) {
    int nt = (n0 >> 4) + w;
    const _Float16* src = jb.Bpk + ((size_t)(kt * 48 + nt) * 64 + lane) * 8;
    __builtin_amdgcn_global_load_lds(
        (const AS1 unsigned int*)src,
        (AS3 unsigned int*)&Bl[buf][w * 512 + lane * 8], 16, 0, 0);
  };

  loadA(0);
  stageB(0, 0);
  writeA(0);
  floatx4 acc[4] = {};

  for (int kt = 0; kt < KT; ++kt) {
    const int buf = kt & 1;
    __syncthreads();                       // buf fully staged for all waves
    if (kt + 1 < KT) { loadA(kt + 1); stageB(kt + 1, buf ^ 1); }
    half8 bf = *(const half8*)&Bl[buf][w * 512 + lane * 8];
#pragma unroll
    for (int st = 0; st < 4; ++st) {
      half8 af = *(const half8*)&Al[buf][(st * 16 + l15) * 40 + quad * 8];
      acc[st] = __builtin_amdgcn_mfma_f32_16x16x32_f16(af, bf, acc[st], 0, 0, 0);
    }
    if (kt + 1 < KT) writeA(buf ^ 1);      // buf^1 free: all reads done pre-sync
  }

  // epilogue: bias + fragment-packed fp16 G stores
  int col = n0 + w * 16 + l15;
  float bb = jb.bias[col];
  int g = col >> 8, kk = col & 255;
  int ww = kk >> 5, ss = (kk >> 4) & 1, ll = kk & 15;
  int cc = 2 * g + ss;
#pragma unroll
  for (int st = 0; st < 4; ++st) {
#pragma unroll
    for (int r = 0; r < 4; ++r) {
      int grow = m0 + st * 16 + quad * 4 + r;
      int b = grow >> tcsh, tl = grow & (tc - 1);
      int rg = b >> 4, mm = b & 15, qb = mm >> 2, rb = mm & 3;
      jb.G[((size_t)tl * BATCH + rg * RPB) * NG +
           ((ww * 6 + cc) * 64 + qb * 16 + ll) * 4 + rb] =
          (_Float16)(acc[st][r] + bb);
    }
  }
}

// ---------------------------------------------------------------------------
// Persistent-weight fused GRU block. fp16 G staged into 4 LDS buffers,
// prefetch depth 3, exact counted vmcnt per iteration.
// ---------------------------------------------------------------------------
__device__ __forceinline__ void gru_block(const GruJob& jb, int rg, SMem& sm)
{
  _Float16* hpk = sm.g.hpk;
  _Float16* rpk = sm.g.rpk;
  auto& Gs = sm.g.Gs;

  const _Float16* G = jb.G;
  if (!G) return;
  const _Float16* Wsrc = jb.W;
  _Float16* outp = jb.outp;
  float* state = jb.state;
  const int t0 = jb.t0, tc = jb.tc;

  const int tid = threadIdx.x;
  const int w = tid >> 6, lane = tid & 63;
  const int quad = lane >> 4, l15 = lane & 15;

  // --- load weights once; pin (blocks rematerialization/sinking) ----------
  floatx4 wg[4][8];   // gate tiles -> VGPRs
  floatx4 wc[2][8];   // candidate tiles -> AGPRs
#pragma unroll
  for (int i = 0; i < 4; ++i) {
    const int tile = (i >> 1) * 16 + w * 2 + (i & 1);
#pragma unroll
    for (int kt = 0; kt < 8; ++kt) {
      wg[i][kt] = *(const floatx4*)&Wsrc[((size_t)(tile * 8 + kt) * 64 + lane) * 8];
      asm volatile("" : "+v"(wg[i][kt]));
    }
  }
#pragma unroll
  for (int i = 0; i < 2; ++i) {
    const int tile = 32 + w * 2 + i;
#pragma unroll
    for (int kt = 0; kt < 8; ++kt) {
      wc[i][kt] = *(const floatx4*)&Wsrc[((size_t)(tile * 8 + kt) * 64 + lane) * 8];
      asm volatile("" : "+a"(wc[i][kt]));
    }
  }

  // --- seq / steps ---------------------------------------------------------
  int seq4[4];
#pragma unroll
  for (int r = 0; r < 4; ++r) seq4[r] = jb.seq[rg * RPB + quad * 4 + r];
  int Smax = 0;
#pragma unroll
  for (int i = 0; i < 16; ++i) Smax = max(Smax, jb.seq[rg * RPB + i]);
  int steps = Smax - t0;
  if (steps < 0) steps = 0;
  if (steps > tc) steps = tc;

  // --- frag addressing (R7-validated bank-exact layout) --------------------
  const int wbase = (w * 64 + quad * 2 + (l15 >> 3)) * 8 + (l15 & 7);
  const int rbase = (((quad >> 1) << 5) + ((l15 & 3) << 3) +
                     ((l15 >> 2) << 1) + (quad & 1)) * 8;

  // --- h_reg init + h frag fill -------------------------------------------
  float h_reg[2][4];
#pragma unroll
  for (int s = 0; s < 2; ++s)
#pragma unroll
    for (int r = 0; r < 4; ++r) {
      int row = quad * 4 + r, k = w * 32 + s * 16 + l15;
      float v = (t0 == 0) ? 0.f : state[(size_t)(rg * RPB + row) * H_ + k];
      h_reg[s][r] = v;
      hpk[wbase + s * 256 + r * 64] = (_Float16)v;
    }

  // --- async fp16 G staging: wave w copies its own 3 KB slice -------------
  const _Float16* gblk = G + (size_t)rg * RPB * NG + w * 1536;
  _Float16* ldsw = &Gs[0][0] + w * 1536;
  auto stage = [&](int t, int buf) {
    const _Float16* gp = gblk + (size_t)t * BATCH * NG;
    _Float16* lp = ldsw + buf * 12288;
#pragma unroll
    for (int i = 0; i < 3; ++i) {
      __builtin_amdgcn_global_load_lds(
          (const AS1 unsigned int*)(gp + i * 512 + lane * 8),
          (AS3 unsigned int*)(lp + i * 512), 16, 0, 0);
    }
  };
  if (steps > 0) stage(0, 0);
  __syncthreads();   // drain: t=0 loads complete + hpk visible
  if (steps > 1) stage(1, 1);   // issued post-barrier: latency hides under t=0
  if (steps > 2) stage(2, 2);

  const _Float16* hA = &hpk[rbase];
  const _Float16* rA = &rpk[rbase];

  __builtin_amdgcn_s_setprio(1);
  for (int t = 0; t < steps; ++t) {
    const int buf = t & 3;
    if (t + 3 < steps) stage(t + 3, (t + 3) & 3);   // depth-3 prefetch

    // ---------------- phase A: 4 gate tiles (r s=0,1 ; u s=0,1) ----------
    floatx4 acc[4] = {};
#pragma unroll
    for (int kt = 0; kt < 8; ++kt) {
      half8 a = *(const half8*)&hA[kt * 512];
#pragma unroll
      for (int s = 0; s < 4; ++s)
        acc[s] = __builtin_amdgcn_mfma_f32_16x16x32_f16(
            a, __builtin_bit_cast(half8, wg[s][kt]), acc[s], 0, 0, 0);
    }

    // exact counted wait: stage(t) loads are the oldest; newer vmem ops =
    // 8 stores per executed phase-B (min(t,3), outp only) + 3 loads per
    // issued future stage (min(3, steps-1-t)).
    {
      int np = outp ? ((t < 3) ? t : 3) : 0;
      int nf = steps - 1 - t; if (nf > 3) nf = 3;
      switch (np * 4 + nf) {
        case  0: __builtin_amdgcn_s_waitcnt(WCVM(0));  break;
        case  1: __builtin_amdgcn_s_waitcnt(WCVM(3));  break;
        case  2: __builtin_amdgcn_s_waitcnt(WCVM(6));  break;
        case  3: __builtin_amdgcn_s_waitcnt(WCVM(9));  break;
        case  4: __builtin_amdgcn_s_waitcnt(WCVM(8));  break;
        case  5: __builtin_amdgcn_s_waitcnt(WCVM(11)); break;
        case  6: __builtin_amdgcn_s_waitcnt(WCVM(14)); break;
        case  7: __builtin_amdgcn_s_waitcnt(WCVM(17)); break;
        case  8: __builtin_amdgcn_s_waitcnt(WCVM(16)); break;
        case  9: __builtin_amdgcn_s_waitcnt(WCVM(19)); break;
        case 10: __builtin_amdgcn_s_waitcnt(WCVM(22)); break;
        case 11: __builtin_amdgcn_s_waitcnt(WCVM(25)); break;
        case 12: __builtin_amdgcn_s_waitcnt(WCVM(24)); break;
        case 13: __builtin_amdgcn_s_waitcnt(WCVM(27)); break;
        case 14: __builtin_amdgcn_s_waitcnt(WCVM(30)); break;
        default: __builtin_amdgcn_s_waitcnt(WCVM(33)); break;
      }
    }

    floatx4 gA[4];
#pragma unroll
    for (int c = 0; c < 4; ++c) {
      half4 hv = *(const half4*)&Gs[buf][(w * 6 + c) * 256 + lane * 4];
#pragma unroll
      for (int j = 0; j < 4; ++j) gA[c][j] = (float)hv[j];
    }

#pragma unroll
    for (int s = 0; s < 2; ++s)
#pragma unroll
      for (int r = 0; r < 4; ++r) {
        float pre = acc[s][r] + gA[s][r];
        float g = __builtin_amdgcn_rcpf(1.f + __expf(-pre));
        rpk[wbase + s * 256 + r * 64] = (_Float16)(g * h_reg[s][r]);
      }
    float u_reg[2][4];
#pragma unroll
    for (int s = 0; s < 2; ++s)
#pragma unroll
      for (int r = 0; r < 4; ++r) {
        float pre = acc[2 + s][r] + gA[2 + s][r];
        u_reg[s][r] = __builtin_amdgcn_rcpf(1.f + __expf(-pre));
      }
    __builtin_amdgcn_s_waitcnt(WC_LGKM0);   // rpk visible
    __builtin_amdgcn_s_barrier();

    // ---------------- phase B: 2 candidate tiles --------------------------
    floatx4 accB[2] = {};
#pragma unroll
    for (int kt = 0; kt < 8; ++kt) {
      half8 a = *(const half8*)&rA[kt * 512];
#pragma unroll
      for (int s = 0; s < 2; ++s)
        accB[s] = __builtin_amdgcn_mfma_f32_16x16x32_f16(
            a, __builtin_bit_cast(half8, wc[s][kt]), accB[s], 0, 0, 0);
    }
    floatx4 gB[2];
#pragma unroll
    for (int s = 0; s < 2; ++s) {
      half4 hv = *(const half4*)&Gs[buf][(w * 6 + 4 + s) * 256 + lane * 4];
#pragma unroll
      for (int j = 0; j < 4; ++j) gB[s][j] = (float)hv[j];
    }

#pragma unroll
    for (int s = 0; s < 2; ++s)
#pragma unroll
      for (int r = 0; r < 4; ++r) {
        int row = quad * 4 + r;
        float pre = accB[s][r] + gB[s][r];
        float c = 1.f - 2.f * __builtin_amdgcn_rcpf(1.f + __expf(2.f * pre));
        float u = u_reg[s][r];
        float hn = u * h_reg[s][r] + (1.f - u) * c;
        bool valid = (t0 + t) < seq4[r];
        hn = valid ? hn : h_reg[s][r];
        h_reg[s][r] = hn;
        hpk[wbase + s * 256 + r * 64] = (_Float16)hn;
        if (outp)
          outp[((size_t)(rg * RPB + row) * tc + t) * H_ + (w * 32 + s * 16 + l15)] =
              (_Float16)(valid ? hn : 0.f);
      }
    __builtin_amdgcn_s_waitcnt(WC_LGKM0);   // hpk visible
    __builtin_amdgcn_s_barrier();
  }
  __builtin_amdgcn_s_setprio(0);
  // --- save state from fp32 masters ---------------------------------------
#pragma unroll
  for (int s = 0; s < 2; ++s)
#pragma unroll
    for (int r = 0; r < 4; ++r)
      state[(size_t)(rg * RPB + quad * 4 + r) * H_ + (w * 32 + s * 16 + l15)] =
          h_reg[s][r];
}

// ---------------------------------------------------------------------------
// Mega dispatch: gru blocks first (get CUs first), gemm blocks fill the rest.
// ---------------------------------------------------------------------------
__global__ __launch_bounds__(512, 1) void mega(StageArgs a)
{
  __shared__ SMem sm;
  const int bid = blockIdx.x;
  const int ngrub = a.ngru * NBLK;
  if (bid < ngrub) {
    gru_block(a.gj[bid >> 3], bid & 7, sm);
  } else {
    int lb = bid - ngrub;
    int j = 0;
#pragma unroll
    for (int k = 1; k < 4; ++k)
      if (k < a.ngemm && lb >= a.goff[k]) j = k;
    gemm_block(a.mj[j], a.emb, lb - a.goff[j], sm);
  }
}

// ---------------------------------------------------------------------------
// Final prediction: out[b, c] = [h_head | h_body] @ W_pred + b_pred.
// ---------------------------------------------------------------------------
__global__ __launch_bounds__(512) void pred_k(
    const float* __restrict__ hh, const float* __restrict__ hb,
    const float* __restrict__ Wp, const float* __restrict__ bpred,
    float* __restrict__ out)
{
  int tid = threadIdx.x;
  int b = tid >> 2, c = tid & 3;
  float acc = bpred[c];
  for (int k = 0; k < H_; ++k) acc += hh[b * H_ + k] * Wp[k * 4 + c];
  for (int k = 0; k < H_; ++k) acc += hb[b * H_ + k] * Wp[(H_ + k) * 4 + c];
  out[b * 4 + c] = acc;
}

// ---------------------------------------------------------------------------
extern "C" void kernel_launch(void* const* d_in, const int* in_sizes, int n_in,
                              void* d_out, int out_size, void* d_ws, size_t ws_size,
                              hipStream_t stream)
{
  (void)in_sizes; (void)n_in; (void)out_size;
  const int*   idsH = (const int*)  d_in[0];
  const int*   idsB = (const int*)  d_in[1];
  const float* emb  = (const float*)d_in[2];
  const float* Wp   = (const float*)d_in[3];
  const float* bp   = (const float*)d_in[4];
  const float* W[4][4];   // [hd0,hd1,bd0,bd1][Wg,bg,Wc,bc]
  for (int s = 0; s < 4; ++s)
    for (int q = 0; q < 4; ++q)
      W[s][q] = (const float*)d_in[5 + s * 4 + q];

  float* wbase = (float*)d_ws;
  size_t off = 0;
  auto alloc = [&](size_t n) {
    float* p = wbase + off; off += (n + 255) & ~(size_t)255; return p;
  };
  int* seqH = (int*)alloc(BATCH);
  int* seqB = (int*)alloc(BATCH);
  float* bi[4]; _Float16* Wpk[4]; _Float16* Bxh[4];
  const int din[4] = {E_, H_, E_, H_};
  const int KT[4]  = {10, 8, 10, 8};        // ceil(din/32)
  for (int s = 0; s < 4; ++s) {
    bi[s]  = alloc(NG);
    Wpk[s] = (_Float16*)alloc(48 * 8 * 64 * 8 / 2);
    Bxh[s] = (_Float16*)alloc((size_t)KT[s] * 48 * 64 * 8 / 2);
  }
  float* stB0 = alloc((size_t)BATCH * H_);
  float* stH0 = alloc((size_t)BATCH * H_);
  float* hfH  = alloc((size_t)BATCH * H_);
  float* hfB  = alloc((size_t)BATCH * H_);

  // headline buffers (single-buffered; head jobs are spaced 2 stages apart)
  const int CHH = 16;                        // TH/CHH = 2 head chunks
  _Float16* GH0 = (_Float16*)alloc((size_t)BATCH * CHH * NG / 2);
  _Float16* GH1 = (_Float16*)alloc((size_t)BATCH * CHH * NG / 2);
  _Float16* OcH = (_Float16*)alloc((size_t)BATCH * CHH * H_ / 2);

  // body chunk size: 16 steps (falls back if ws is tight)
  int CH = 16;
  while (CH > 4 &&
         (off + (size_t)BATCH * CH * (2 * NG + H_) + 2048) * 4 > ws_size)
    CH >>= 1;
  _Float16 *GB0[2], *GB1[2], *OcB[2];
  for (int i = 0; i < 2; ++i) {
    GB0[i] = (_Float16*)alloc((size_t)BATCH * CH * NG / 2);
    GB1[i] = (_Float16*)alloc((size_t)BATCH * CH * NG / 2);
    OcB[i] = (_Float16*)alloc((size_t)BATCH * CH * H_ / 2);
  }
  const int tcshB = __builtin_ctz(CH), tcshH = __builtin_ctz(CHH);
  const int NB = TB_ / CH;

  // 1. pack weights + seqlens
  for (int s = 0; s < 4; ++s) {
    pack_bias<<<(NG + 255) / 256, 256, 0, stream>>>(W[s][1], W[s][3], bi[s]);
    pack_w<<<(48 * 64 + 255) / 256, 256, 0, stream>>>(
        W[s][0], W[s][2], din[s], Wpk[s]);
    pack_bx<<<(KT[s] * 48 * 64 + 255) / 256, 256, 0, stream>>>(
        W[s][0], W[s][2], din[s], KT[s], Bxh[s]);
  }
  seq_k<<<BATCH, 256, 0, stream>>>(idsH, TH_, seqH);
  seq_k<<<BATCH, 256, 0, stream>>>(idsB, TB_, seqB);

  // 2. lag-2 software pipeline of mega dispatches.
  //    Stage s: gemm0(s) | gruL0(s-1) | gemm1(s-2) | gruL1(s-3)   (body)
  //    Headline rides along in stages 0..5 at half rate (single buffers).
  const int nstages = (NB + 3 > 6) ? NB + 3 : 6;
  for (int s = 0; s < nstages; ++s) {
    StageArgs a{};
    a.emb = emb;
    int ng = 0, nm = 0, gacc = 0;
    auto addGru = [&](const _Float16* G, const _Float16* Wk, const int* seq,
                      _Float16* outp, float* st, int t0, int tc) {
      a.gj[ng++] = GruJob{G, Wk, seq, outp, st, t0, tc};
    };
    auto addGemm = [&](const _Float16* Adir, const int* ids, const _Float16* Bpk,
                       const float* bias, _Float16* G, int K, int KTv, int t0,
                       int tcsh, int T, int rows) {
      a.goff[nm] = gacc; gacc += (rows / 64) * 6;
      a.mj[nm++] = GemmJob{Adir, ids, Bpk, bias, G, K, KTv, t0, tcsh, T};
    };

    // ---- body ----
    if (s < NB)
      addGemm(nullptr, idsB, Bxh[2], bi[2], GB0[s & 1], E_, 10, s * CH,
              tcshB, TB_, BATCH * CH);
    if (s >= 1 && s <= NB) {
      int c = s - 1;
      addGru(GB0[c & 1], Wpk[2], seqB, OcB[c & 1], stB0, c * CH, CH);
    }
    if (s >= 2 && s <= NB + 1) {
      int c = s - 2;
      addGemm(OcB[c & 1], nullptr, Bxh[3], bi[3], GB1[c & 1], H_, 8, 0,
              tcshB, TB_, BATCH * CH);
    }
    if (s >= 3 && s <= NB + 2) {
      int c = s - 3;
      addGru(GB1[c & 1], Wpk[3], seqB, nullptr, hfB, c * CH, CH);
    }
    // ---- headline ----
    if (s == 0 || s == 2)
      addGemm(nullptr, idsH, Bxh[0], bi[0], GH0, E_, 10, (s >> 1) * CHH,
              tcshH, TH_, BATCH * CHH);
    if (s == 1 || s == 3)
      addGru(GH0, Wpk[0], seqH, OcH, stH0, ((s - 1) >> 1) * CHH, CHH);
    if (s == 2 || s == 4)
      addGemm(OcH, nullptr, Bxh[1], bi[1], GH1, H_, 8, 0, tcshH, TH_,
              BATCH * CHH);
    if (s == 3 || s == 5)
      addGru(GH1, Wpk[1], seqH, nullptr, hfH, ((s - 3) >> 1) * CHH, CHH);

    a.ngru = ng; a.ngemm = nm;
    int nblocks = ng * NBLK + gacc;
    if (nblocks > 0) mega<<<nblocks, 512, 0, stream>>>(a);
  }

  // 3. prediction head
  pred_k<<<1, 512, 0, stream>>>(hfH, hfB, Wp, bp, (float*)d_out);
}